// Round 2
// baseline (92793.683 us; speedup 1.0000x reference)
//
#include <hip/hip_runtime.h>
#include <math.h>

#define B_ 16
#define S_ 512
#define FRAME_ 438
#define DM_ 800
#define H_ 8
#define DH_ 100
#define FFN_ 1024
#define HID_ 1024
#define POSE_ 274
#define WIN_ 100
#define G4_ 4096     // 4*HID
#define KPA_ 1536    // padded K for WT_A ([Wh;Wx], K=1298)
#define KPB_ 2048    // padded K for WT_B ([WEFF;G2], K=1824)
#define NBLK_SCAN 512
#define WLS_ 1312    // LDS row stride for WT_A slice (>=1298, mult of 4)
#define WLSZ_ (8 * WLS_ + 256)  // + zero tail: last row reads up to WLS_+223 past

// ---------------------------------------------------------------------------
// gemm128: fp32, 128x128 tile, 256 thr, 8x8 micro (split 4+4, conflict-free
// LDS). C = A@B (+bias[N]) (+res[M,N]) (+pos_table[posidx[m]]) (relu).
// ---------------------------------------------------------------------------
__global__ __launch_bounds__(256) void gemm128(
    const float* __restrict__ A, const float* __restrict__ Bm,
    float* __restrict__ C, int M, int N, int K,
    const float* __restrict__ bias, const float* __restrict__ res,
    const int* __restrict__ posidx, const float* __restrict__ postab,
    int relu)
{
    __shared__ float As[16 * 132];
    __shared__ float Bs[16 * 132];
    int m0 = blockIdx.x * 128, n0 = blockIdx.y * 128;
    int tid = threadIdx.x;
    int tx = tid & 15, ty = tid >> 4;
    float acc[8][8];
#pragma unroll
    for (int i = 0; i < 8; ++i)
#pragma unroll
        for (int j = 0; j < 8; ++j) acc[i][j] = 0.f;

    for (int k0 = 0; k0 < K; k0 += 16) {
#pragma unroll
        for (int i = 0; i < 8; ++i) {             // A: 128 m x 16 k
            int idx = i * 256 + tid;
            int m = idx >> 4, kl = idx & 15;
            int r = m0 + m, k = k0 + kl;
            As[kl * 132 + m] = (r < M && k < K) ? A[(long)r * K + k] : 0.f;
        }
#pragma unroll
        for (int i = 0; i < 8; ++i) {             // B: 16 k x 128 n
            int idx = i * 256 + tid;
            int n = idx & 127, k = idx >> 7;
            int kk = k0 + k, nn = n0 + n;
            Bs[k * 132 + n] = (kk < K && nn < N) ? Bm[(long)kk * N + nn] : 0.f;
        }
        __syncthreads();
#pragma unroll
        for (int kk = 0; kk < 16; ++kk) {
            float4 a0 = *(const float4*)&As[kk * 132 + ty * 4];
            float4 a1 = *(const float4*)&As[kk * 132 + 64 + ty * 4];
            float4 b0 = *(const float4*)&Bs[kk * 132 + tx * 4];
            float4 b1 = *(const float4*)&Bs[kk * 132 + 64 + tx * 4];
            float a[8] = {a0.x, a0.y, a0.z, a0.w, a1.x, a1.y, a1.z, a1.w};
            float b[8] = {b0.x, b0.y, b0.z, b0.w, b1.x, b1.y, b1.z, b1.w};
#pragma unroll
            for (int i = 0; i < 8; ++i)
#pragma unroll
                for (int j = 0; j < 8; ++j) acc[i][j] += a[i] * b[j];
        }
        __syncthreads();
    }
#pragma unroll
    for (int i = 0; i < 8; ++i) {
        int m = m0 + ((i < 4) ? (ty * 4 + i) : (64 + ty * 4 + i - 4));
        if (m >= M) continue;
#pragma unroll
        for (int j = 0; j < 8; ++j) {
            int n = n0 + ((j < 4) ? (tx * 4 + j) : (64 + tx * 4 + j - 4));
            if (n >= N) continue;
            float v = acc[i][j];
            if (bias) v += bias[n];
            if (res) v += res[(long)m * N + n];
            if (posidx) v += postab[(long)posidx[m] * N + n];
            if (relu) v = fmaxf(v, 0.f);
            C[(long)m * N + n] = v;
        }
    }
}

// ---------------------------------------------------------------------------
// LayerNorm over last dim N (=800), one block per row.
// ---------------------------------------------------------------------------
__global__ __launch_bounds__(256) void ln_f32(
    const float* __restrict__ X, float* __restrict__ Y,
    const float* __restrict__ g, const float* __restrict__ b, int N)
{
    int m = blockIdx.x;
    const float* x = X + (long)m * N;
    __shared__ float red[256];
    int tid = threadIdx.x;
    float s = 0.f;
    for (int i = tid; i < N; i += 256) s += x[i];
    red[tid] = s; __syncthreads();
    for (int o = 128; o > 0; o >>= 1) { if (tid < o) red[tid] += red[tid + o]; __syncthreads(); }
    float mean = red[0] / N;
    __syncthreads();
    float v = 0.f;
    for (int i = tid; i < N; i += 256) { float d = x[i] - mean; v += d * d; }
    red[tid] = v; __syncthreads();
    for (int o = 128; o > 0; o >>= 1) { if (tid < o) red[tid] += red[tid + o]; __syncthreads(); }
    float rs = rsqrtf(red[0] / N + 1e-6f);
    for (int i = tid; i < N; i += 256)
        Y[(long)m * N + i] = (x[i] - mean) * rs * g[i] + b[i];
}

// ---------------------------------------------------------------------------
// Fused banded attention (verified round 1).
// ---------------------------------------------------------------------------
__global__ __launch_bounds__(256) void attn_f32(
    const float* __restrict__ Q, const float* __restrict__ K,
    const float* __restrict__ V, float* __restrict__ O)
{
    int blk = blockIdx.x;
    int qt = blk & 127; int bh = blk >> 7;
    int h = bh & 7; int b = bh >> 3;
    int q0 = qt * 4;
    int tid = threadIdx.x;

    __shared__ float qv[4][DH_];
    __shared__ float sc[4][208];
    __shared__ float red[256];
    __shared__ float inv_den[4];

    for (int i = tid; i < 4 * DH_; i += 256) {
        int qi = i / DH_, d = i - qi * DH_;
        qv[qi][d] = Q[(long)(b * S_ + q0 + qi) * DM_ + h * DH_ + d];
    }
    __syncthreads();

    int w = tid;
    int k = q0 - WIN_ + w;
    bool kvalid = (w < 204) && (k >= 0) && (k < S_);
    float dots[4] = {0.f, 0.f, 0.f, 0.f};
    if (kvalid) {
        const float* krow = K + (long)(b * S_ + k) * DM_ + h * DH_;
        for (int d = 0; d < DH_; ++d) {
            float kvv = krow[d];
#pragma unroll
            for (int qi = 0; qi < 4; ++qi) dots[qi] += qv[qi][d] * kvv;
        }
    }
#pragma unroll
    for (int qi = 0; qi < 4; ++qi) {
        int wq = w - qi;
        if (w < 204 && wq >= 0 && wq < 201)
            sc[qi][wq] = kvalid ? dots[qi] * 0.1f : -1e30f;
    }
    __syncthreads();

    for (int qi = 0; qi < 4; ++qi) {
        float vmax = (tid < 201) ? sc[qi][tid] : -1e30f;
        red[tid] = vmax; __syncthreads();
        for (int o = 128; o > 0; o >>= 1) { if (tid < o) red[tid] = fmaxf(red[tid], red[tid + o]); __syncthreads(); }
        float mx = red[0];
        __syncthreads();
        float e = 0.f;
        if (tid < 201) { e = __expf(sc[qi][tid] - mx); sc[qi][tid] = e; }
        red[tid] = e; __syncthreads();
        for (int o = 128; o > 0; o >>= 1) { if (tid < o) red[tid] += red[tid + o]; __syncthreads(); }
        if (tid == 0) inv_den[qi] = 1.f / red[0];
        __syncthreads();
    }

    if (tid < DH_) {
        int d = tid;
        float o_[4] = {0.f, 0.f, 0.f, 0.f};
        for (int w2 = 0; w2 < 204; ++w2) {
            int k2 = q0 - WIN_ + w2;
            if (k2 < 0 || k2 >= S_) continue;
            float vv = V[(long)(b * S_ + k2) * DM_ + h * DH_ + d];
#pragma unroll
            for (int qi = 0; qi < 4; ++qi) {
                int wq = w2 - qi;
                if (wq >= 0 && wq < 201) o_[qi] += sc[qi][wq] * vv;
            }
        }
#pragma unroll
        for (int qi = 0; qi < 4; ++qi)
            O[(long)(b * S_ + q0 + qi) * DM_ + h * DH_ + d] = o_[qi] * inv_den[qi];
    }
}

// g3[j] = out_b @ Wx
__global__ __launch_bounds__(256) void g3_kernel(
    const float* __restrict__ outb, const float* __restrict__ Wx, float* __restrict__ g3)
{
    int j = blockIdx.x * 256 + threadIdx.x;
    if (j >= G4_) return;
    float s = 0.f;
    for (int p = 0; p < POSE_; ++p) s += outb[p] * Wx[(long)p * G4_ + j];
    g3[j] = s;
}

// init h state + zero the grid-barrier counters (1088 uints)
__global__ __launch_bounds__(256) void init_state(
    const float* __restrict__ vh, float* __restrict__ h0,
    unsigned* __restrict__ bar)
{
    int i = blockIdx.x * 256 + threadIdx.x;
    if (i < B_ * HID_) h0[i] = vh[i];
    if (i < 1088) bar[i] = 0u;
}

// ---------------------------------------------------------------------------
// tr_cat: WT[c][k] = (k<K1 ? in1[k][c] : k<K1+K2 ? in2[k-K1][c] : 0)
// ---------------------------------------------------------------------------
__global__ __launch_bounds__(256) void tr_cat(
    const float* __restrict__ in1, const float* __restrict__ in2,
    float* __restrict__ WT, int K1, int K2, int KP)
{
    __shared__ float tile[64][65];
    int k0 = blockIdx.x * 64, c0 = blockIdx.y * 64;
    int tid = threadIdx.x;
    int cl = tid & 63, kr = tid >> 6;
#pragma unroll
    for (int i = 0; i < 16; ++i) {
        int kl = i * 4 + kr;
        int k = k0 + kl, c = c0 + cl;
        float v = 0.f;
        if (k < K1) v = in1[(long)k * G4_ + c];
        else if (k < K1 + K2) v = in2[(long)(k - K1) * G4_ + c];
        tile[kl][cl] = v;
    }
    __syncthreads();
    int kl2 = tid & 63, cr = tid >> 6;
#pragma unroll
    for (int i = 0; i < 16; ++i) {
        int ci = i * 4 + cr;
        WT[(long)(c0 + ci) * KP + k0 + kl2] = tile[kl2][ci];
    }
}

// ---------------------------------------------------------------------------
// Fence-free two-level grid barrier. ALL atomics RELAXED (no L2 wb/inv --
// that was round 1's 47us/step killer). Cross-XCD data (h) moves via
// agent-scope relaxed atomic ld/st (sc0+sc1: coherent at L3), so no cache
// maintenance is needed; weights/tgt/ENC stay hot in per-XCD L2.
// Ordering: __syncthreads drains vmcnt (h stores at L3) before arrival;
// atomic RMW return values chain arrivals -> root -> gen at the L3 point.
// ---------------------------------------------------------------------------
__device__ __forceinline__ void grid_sync(unsigned* __restrict__ gcnt,
                                          unsigned* __restrict__ root,
                                          unsigned* __restrict__ gen, int step)
{
    __syncthreads();                       // vmcnt(0): h stores visible at L3
    if (threadIdx.x == 0) {
        unsigned grp = (unsigned)blockIdx.x >> 4;           // 32 groups x 16 blk
        unsigned tk = __hip_atomic_fetch_add(&gcnt[grp * 32], 1u,
                          __ATOMIC_RELAXED, __HIP_MEMORY_SCOPE_AGENT);
        if (tk == (unsigned)(16 * step + 15)) {             // last in group
            unsigned r = __hip_atomic_fetch_add(root, 1u,
                             __ATOMIC_RELAXED, __HIP_MEMORY_SCOPE_AGENT);
            if (r == (unsigned)(32 * step + 31))            // last group
                __hip_atomic_store(gen, (unsigned)(step + 1),
                    __ATOMIC_RELAXED, __HIP_MEMORY_SCOPE_AGENT);
        }
        while (__hip_atomic_load(gen, __ATOMIC_RELAXED,
                   __HIP_MEMORY_SCOPE_AGENT) <= (unsigned)step)
            __builtin_amdgcn_s_sleep(4);
    }
    __syncthreads();
}

// ---------------------------------------------------------------------------
// lstm_scan v2: persistent, weights-in-LDS.
// - WT_A rows (8 per block, 91% of steps) copied to LDS ONCE -> zero global
//   weight traffic on A-steps. Row stride 1312 (valid K=1298; pan is zero
//   beyond, and reads past a row's stride hit finite data x 0 = 0; tail
//   region explicitly zeroed to avoid NaN*0).
// - h exchanged via agent-scope relaxed atomics (L3-coherent, no fences),
//   software-pipelined: next h-panel prefetched into regs during compute.
// - c-state lives in registers of lanes 0..31 (block-private).
// - B-steps (t%per==0, ~46 of 512) stream WT_B with NORMAL cached loads --
//   L2 stays valid across steps now, so these are L2-hot after first use.
// A-step FMA order is bitwise identical to the verified lstm_step3.
// LDS: WL 43KB + pan/red/gst union 17.4KB = 60.4KB -> 2 blocks/CU.
// ---------------------------------------------------------------------------
__global__ __launch_bounds__(256, 2) void lstm_scan(
    float* __restrict__ HB0, float* __restrict__ HB1,
    const float* __restrict__ vec_c,
    const float* __restrict__ WT_A, const float* __restrict__ WT_B,
    const float* __restrict__ g3, const float* __restrict__ lstm_b,
    const int* __restrict__ epoch,
    const float* __restrict__ tgt, const float* __restrict__ dec0,
    const float* __restrict__ ENC, float* __restrict__ Hall,
    unsigned* __restrict__ bar)
{
    __shared__ float WL[WLSZ_];       // 8 WT_A rows, stride WLS_
    __shared__ float pan[256 * 17];   // panel; reused as red[0..2303], gst[2304..]
    float* red = pan;
    float* gst = pan + 2304;

    int tid = threadIdx.x;
    int hid0 = blockIdx.x * 2;
    int kq = tid >> 4, b = tid & 15;
    int b3 = tid >> 1, hh = tid & 1;
    int p = (int)((double)epoch[0] * 0.01);   // match python int(epoch*LAMB)
    int per = p + 10;
    unsigned* gcnt = bar;
    unsigned* root = bar + 1024;
    unsigned* gen  = bar + 1056;

    // ---- one-time: stage this block's 8 WT_A rows into LDS ----
#pragma unroll
    for (int c = 0; c < 8; ++c) {
        const float* src = WT_A + (long)((c >> 1) * 1024 + hid0 + (c & 1)) * KPA_;
        for (int i = tid * 4; i < WLS_; i += 1024)
            *(float4*)&WL[c * WLS_ + i] = *(const float4*)&src[i];
    }
    for (int i = 8 * WLS_ + tid; i < WLSZ_; i += 256) WL[i] = 0.f;  // NaN guard

    // ---- c-state in registers (lane tid<32 owns (b3, hid0+hh)) ----
    float c_reg = 0.f;
    if (tid < 32) c_reg = vec_c[b3 * HID_ + hid0 + hh];
    __syncthreads();

    for (int t = 0; t < S_; ++t) {
        bool msk = (t % per) >= p;
        bool useA = msk || (t == 0);
        const float* hread  = (t & 1) ? HB1 : HB0;
        float*       hwrite = (t & 1) ? HB0 : HB1;

        float acc[8] = {0.f, 0.f, 0.f, 0.f, 0.f, 0.f, 0.f, 0.f};

        // prefetch h-panel 0 (agent-scope: L1/L2-bypass, L3-fresh)
        float hpre[16];
#pragma unroll
        for (int bb = 0; bb < 16; ++bb)
            hpre[bb] = __hip_atomic_load(&hread[bb * 1024 + tid],
                           __ATOMIC_RELAXED, __HIP_MEMORY_SCOPE_AGENT);

        if (useA) {
            for (int P = 0; P < KPA_; P += 256) {
                if (P < 1024) {
#pragma unroll
                    for (int bb = 0; bb < 16; ++bb)
                        pan[tid * 17 + bb] = hpre[bb];
                } else {
                    int kx = P - 1024 + tid;
#pragma unroll
                    for (int bb = 0; bb < 16; ++bb) {
                        float v = 0.f;
                        if (kx < POSE_)
                            v = msk ? tgt[((long)bb * S_ + t) * POSE_ + kx]
                                    : dec0[bb * POSE_ + kx];
                        pan[tid * 17 + bb] = v;
                    }
                }
                __syncthreads();
                if (P + 256 < 1024) {          // prefetch next h-panel
#pragma unroll
                    for (int bb = 0; bb < 16; ++bb)
                        hpre[bb] = __hip_atomic_load(
                            &hread[bb * 1024 + P + 256 + tid],
                            __ATOMIC_RELAXED, __HIP_MEMORY_SCOPE_AGENT);
                }
                int kb = P + kq * 16;
#pragma unroll
                for (int j4 = 0; j4 < 4; ++j4) {
                    float4 w[8];
#pragma unroll
                    for (int c = 0; c < 8; ++c)
                        w[c] = *(const float4*)&WL[c * WLS_ + kb + j4 * 4];
                    float h0 = pan[(kq * 16 + j4 * 4 + 0) * 17 + b];
                    float h1 = pan[(kq * 16 + j4 * 4 + 1) * 17 + b];
                    float h2 = pan[(kq * 16 + j4 * 4 + 2) * 17 + b];
                    float h3 = pan[(kq * 16 + j4 * 4 + 3) * 17 + b];
#pragma unroll
                    for (int c = 0; c < 8; ++c)
                        acc[c] += w[c].x * h0 + w[c].y * h1 + w[c].z * h2 + w[c].w * h3;
                }
                __syncthreads();
            }
        } else {
            const float* wrow[8];
#pragma unroll
            for (int c = 0; c < 8; ++c)
                wrow[c] = WT_B + (long)((c >> 1) * 1024 + hid0 + (c & 1)) * KPB_;
            for (int P = 0; P < KPB_; P += 256) {
                if (P < 1024) {
#pragma unroll
                    for (int bb = 0; bb < 16; ++bb)
                        pan[tid * 17 + bb] = hpre[bb];
                } else {
                    int kx = P - 1024 + tid;
#pragma unroll
                    for (int bb = 0; bb < 16; ++bb) {
                        float v = 0.f;
                        if (kx < DM_)
                            v = ENC[((long)bb * S_ + (t - 1)) * DM_ + kx];
                        pan[tid * 17 + bb] = v;
                    }
                }
                __syncthreads();
                if (P + 256 < 1024) {          // prefetch next h-panel
#pragma unroll
                    for (int bb = 0; bb < 16; ++bb)
                        hpre[bb] = __hip_atomic_load(
                            &hread[bb * 1024 + P + 256 + tid],
                            __ATOMIC_RELAXED, __HIP_MEMORY_SCOPE_AGENT);
                }
                int kb = P + kq * 16;
#pragma unroll
                for (int j4 = 0; j4 < 4; ++j4) {
                    float4 w[8];
#pragma unroll
                    for (int c = 0; c < 8; ++c)
                        w[c] = *(const float4*)(wrow[c] + kb + j4 * 4);
                    float h0 = pan[(kq * 16 + j4 * 4 + 0) * 17 + b];
                    float h1 = pan[(kq * 16 + j4 * 4 + 1) * 17 + b];
                    float h2 = pan[(kq * 16 + j4 * 4 + 2) * 17 + b];
                    float h3 = pan[(kq * 16 + j4 * 4 + 3) * 17 + b];
#pragma unroll
                    for (int c = 0; c < 8; ++c)
                        acc[c] += w[c].x * h0 + w[c].y * h1 + w[c].z * h2 + w[c].w * h3;
                }
                __syncthreads();
            }
        }

        // ---- reduce 16 k-slices (pan dead; red aliases it) ----
#pragma unroll
        for (int c = 0; c < 8; ++c) red[(b * 16 + kq) * 9 + c] = acc[c];
        __syncthreads();

        if (tid < 128) {
            int ob = tid >> 3, oc = tid & 7;
            float s = 0.f;
#pragma unroll
            for (int q = 0; q < 16; ++q) s += red[(ob * 16 + q) * 9 + oc];
            int gcol = (oc >> 1) * 1024 + hid0 + (oc & 1);
            s += lstm_b[gcol];
            if (!useA) s += g3[gcol];
            gst[oc * 16 + ob] = s;
        }
        __syncthreads();

        if (tid < 32) {
            int hid = hid0 + hh;
            float iv = gst[(0 * 2 + hh) * 16 + b3];
            float fv = gst[(1 * 2 + hh) * 16 + b3];
            float gv = gst[(2 * 2 + hh) * 16 + b3];
            float ov = gst[(3 * 2 + hh) * 16 + b3];
            float ig = 1.f / (1.f + __expf(-iv));
            float fg = 1.f / (1.f + __expf(-fv));
            float og = 1.f / (1.f + __expf(-ov));
            float cn = fg * c_reg + ig * tanhf(gv);
            float hn = og * tanhf(cn);
            c_reg = cn;
            __hip_atomic_store(&hwrite[b3 * HID_ + hid], hn,
                               __ATOMIC_RELAXED, __HIP_MEMORY_SCOPE_AGENT);
            Hall[((long)b3 * S_ + t) * HID_ + hid] = hn;   // normal store (read post-kernel)
        }

        grid_sync(gcnt, root, gen, t);
    }
}

// ---------------------------------------------------------------------------
extern "C" void kernel_launch(void* const* d_in, const int* in_sizes, int n_in,
                              void* d_out, int out_size, void* d_ws, size_t ws_size,
                              hipStream_t stream) {
    const float* src_seq  = (const float*)d_in[0];
    const int*   src_pos  = (const int*)  d_in[1];
    const float* tgt_seq  = (const float*)d_in[2];
    const float* vec_h    = (const float*)d_in[3];
    const float* vec_c    = (const float*)d_in[4];
    const float* dec0     = (const float*)d_in[5];
    const float* emb_W    = (const float*)d_in[6];
    const float* emb_b    = (const float*)d_in[7];
    const float* pos_tab  = (const float*)d_in[8];
    const float* Wq       = (const float*)d_in[9];
    const float* Wk       = (const float*)d_in[10];
    const float* Wv       = (const float*)d_in[11];
    const float* Wo       = (const float*)d_in[12];
    const float* ln1_g    = (const float*)d_in[13];
    const float* ln1_b    = (const float*)d_in[14];
    const float* ffn_W1   = (const float*)d_in[15];
    const float* ffn_b1   = (const float*)d_in[16];
    const float* ffn_W2   = (const float*)d_in[17];
    const float* ffn_b2   = (const float*)d_in[18];
    const float* ln2_g    = (const float*)d_in[19];
    const float* ln2_b    = (const float*)d_in[20];
    const float* lstm_Wx  = (const float*)d_in[21];
    const float* lstm_Wh  = (const float*)d_in[22];
    const float* lstm_b   = (const float*)d_in[23];
    const float* out_W    = (const float*)d_in[24];
    const float* out_b    = (const float*)d_in[25];
    const int*   epoch    = (const int*)  d_in[26];

    // ---- workspace layout (total 41,209,856 floats = 164.8 MB) ----
    float* ws = (float*)d_ws;
    const long NX = (long)B_ * S_ * DM_;           // 6,553,600
    float* X      = ws;                            // enc / residual [0, NX)
    float* R      = X + NX;                        // 34,603,008-float region
    // encoder phase:
    float* Qb     = R;
    float* Kb     = Qb + NX;
    float* Vb     = Kb + NX;
    float* Ob     = Vb + NX;
    float* FFNH   = Ob + NX;                       // 8,388,608
    // decoder phase (aliases into R; encoder scratch dead):
    float* WEFF_t = R;                             // 4,194,304
    float* G2     = R + 4194304;                   // 3,276,800 (dead after tr_cat B)
    float* WT_A   = R + 7471104;                   // 6,291,456 (4096 x 1536)
    float* WT_B   = R + 13762560;                  // 8,388,608 (4096 x 2048)
    float* Hall   = R + 22151168;                  // 8,388,608 (B*S x 1024)
    float* T1     = WEFF_t;                        // 2,244,608 (after WT_B built)
    float* TAIL   = R + 34603008;
    float* G3v    = TAIL;                          // 4096
    float* HB0    = G3v + G4_;                     // 16384
    float* HB1    = HB0 + B_ * HID_;
    float* CB     = HB1 + B_ * HID_;               // (unused: c now in regs)
    (void)CB;
    // barrier counters live in the dead G2 region (zeroed after tr_cat B)
    unsigned* BAR = (unsigned*)G2;                 // 1088 uints

    const int M = B_ * S_; // 8192
    dim3 blk(256);

    // ---- encoder ----
    gemm128<<<dim3(M / 128, (DM_ + 127) / 128), blk, 0, stream>>>(
        src_seq, emb_W, X, M, DM_, FRAME_, emb_b, nullptr, src_pos, pos_tab, 0);
    gemm128<<<dim3(M / 128, (DM_ + 127) / 128), blk, 0, stream>>>(
        X, Wq, Qb, M, DM_, DM_, nullptr, nullptr, nullptr, nullptr, 0);
    gemm128<<<dim3(M / 128, (DM_ + 127) / 128), blk, 0, stream>>>(
        X, Wk, Kb, M, DM_, DM_, nullptr, nullptr, nullptr, nullptr, 0);
    gemm128<<<dim3(M / 128, (DM_ + 127) / 128), blk, 0, stream>>>(
        X, Wv, Vb, M, DM_, DM_, nullptr, nullptr, nullptr, nullptr, 0);
    attn_f32<<<dim3(B_ * H_ * (S_ / 4)), blk, 0, stream>>>(Qb, Kb, Vb, Ob);
    gemm128<<<dim3(M / 128, (DM_ + 127) / 128), blk, 0, stream>>>(
        Ob, Wo, FFNH, M, DM_, DM_, nullptr, X, nullptr, nullptr, 0);
    ln_f32<<<dim3(M), blk, 0, stream>>>(FFNH, X, ln1_g, ln1_b, DM_);
    gemm128<<<dim3(M / 128, FFN_ / 128), blk, 0, stream>>>(
        X, ffn_W1, FFNH, M, FFN_, DM_, ffn_b1, nullptr, nullptr, nullptr, 1);
    gemm128<<<dim3(M / 128, (DM_ + 127) / 128), blk, 0, stream>>>(
        FFNH, ffn_W2, Ob, M, DM_, FFN_, ffn_b2, X, nullptr, nullptr, 0);
    ln_f32<<<dim3(M), blk, 0, stream>>>(Ob, X, ln2_g, ln2_b, DM_);   // X = enc

    // ---- decoder precompute ----
    // WEFF_t = out_W[:1024]@lstm_Wx + lstm_Wh   (1024 x 4096)
    gemm128<<<dim3(HID_ / 128, G4_ / 128), blk, 0, stream>>>(
        out_W, lstm_Wx, WEFF_t, HID_, G4_, POSE_, nullptr, lstm_Wh, nullptr, nullptr, 0);
    // G2 = out_W[1024:]@lstm_Wx   (800 x 4096)
    gemm128<<<dim3((DM_ + 127) / 128, G4_ / 128), blk, 0, stream>>>(
        out_W + (long)HID_ * POSE_, lstm_Wx, G2, DM_, G4_, POSE_,
        nullptr, nullptr, nullptr, nullptr, 0);
    // transposed, zero-padded step weights
    tr_cat<<<dim3(KPA_ / 64, G4_ / 64), blk, 0, stream>>>(
        lstm_Wh, lstm_Wx, WT_A, HID_, POSE_, KPA_);
    tr_cat<<<dim3(KPB_ / 64, G4_ / 64), blk, 0, stream>>>(
        WEFF_t, G2, WT_B, HID_, DM_, KPB_);
    g3_kernel<<<dim3(G4_ / 256), blk, 0, stream>>>(out_b, lstm_Wx, G3v);
    // init h + zero barrier counters (G2 is dead by now)
    init_state<<<dim3((B_ * HID_ + 255) / 256), blk, 0, stream>>>(
        vec_h, HB0, BAR);
    // T1 = enc@out_W[1024:,:] + out_b  (aliases WEFF_t -> must follow tr_cat)
    gemm128<<<dim3(M / 128, (POSE_ + 127) / 128), blk, 0, stream>>>(
        X, out_W + (long)HID_ * POSE_, T1, M, POSE_, DM_, out_b,
        nullptr, nullptr, nullptr, 0);

    // ---- fused sequential scan: persistent kernel, weights in LDS ----
    lstm_scan<<<dim3(NBLK_SCAN), blk, 0, stream>>>(
        HB0, HB1, vec_c, WT_A, WT_B, G3v, lstm_b, epoch,
        tgt_seq, dec0, X, Hall, BAR);

    // ---- final: out = Hall@out_W[:1024] + T1 ----
    gemm128<<<dim3(M / 128, (POSE_ + 127) / 128), blk, 0, stream>>>(
        Hall, out_W, (float*)d_out, M, POSE_, HID_, nullptr, T1,
        nullptr, nullptr, 0);
}

// Round 3
// 77458.917 us; speedup vs baseline: 1.1980x; 1.1980x over previous
//
#include <hip/hip_runtime.h>
#include <math.h>

#define B_ 16
#define S_ 512
#define FRAME_ 438
#define DM_ 800
#define H_ 8
#define DH_ 100
#define FFN_ 1024
#define HID_ 1024
#define POSE_ 274
#define WIN_ 100
#define G4_ 4096     // 4*HID
#define KPA_ 1536    // padded K for WT_A ([Wh;Wx], K=1298)
#define KPB_ 2048    // padded K for WT_B ([WEFF;G2], K=1824)
#define NBLK_SCAN 512
#define WLS_ 1312    // LDS row stride for WT_A slice (>=1298, mult of 4)
#define WLSZ_ (8 * WLS_ + 256)  // + zero tail: last row reads up to WLS_+223 past

// ---------------------------------------------------------------------------
// Coherent (MALL-point) memory helpers. sc0 sc1 on plain global ops = bypass
// L1+L2, serve at the device-coherent LLC. Coalesced like any vector load
// (unlike per-lane scoped atomics, which round 2 proved are a ~430 MB/step
// uncoalesced RMW disaster). Data h-exchange ONLY uses these.
// ---------------------------------------------------------------------------
__device__ __forceinline__ void ldh16(const float* p, float4& v0, float4& v1,
                                      float4& v2, float4& v3)
{
    asm volatile(
        "global_load_dwordx4 %0, %4, off sc0 sc1\n\t"
        "global_load_dwordx4 %1, %4, off offset:16 sc0 sc1\n\t"
        "global_load_dwordx4 %2, %4, off offset:32 sc0 sc1\n\t"
        "global_load_dwordx4 %3, %4, off offset:48 sc0 sc1\n\t"
        "s_waitcnt vmcnt(0)"
        : "=&v"(v0), "=&v"(v1), "=&v"(v2), "=&v"(v3)
        : "v"(p)
        : "memory");
}

__device__ __forceinline__ void st_coh(float* p, float v)
{
    asm volatile("global_store_dword %0, %1, off sc0 sc1"
                 :: "v"(p), "v"(v) : "memory");
}

__device__ __forceinline__ unsigned ld_coh_u32(const unsigned* p)
{
    unsigned v;
    asm volatile("global_load_dword %0, %1, off sc0 sc1\n\t"
                 "s_waitcnt vmcnt(0)"
                 : "=v"(v) : "v"(p) : "memory");
    return v;
}

// ---------------------------------------------------------------------------
// gemm128: fp32, 128x128 tile, 256 thr, 8x8 micro (split 4+4, conflict-free
// LDS). C = A@B (+bias[N]) (+res[M,N]) (+pos_table[posidx[m]]) (relu).
// ---------------------------------------------------------------------------
__global__ __launch_bounds__(256) void gemm128(
    const float* __restrict__ A, const float* __restrict__ Bm,
    float* __restrict__ C, int M, int N, int K,
    const float* __restrict__ bias, const float* __restrict__ res,
    const int* __restrict__ posidx, const float* __restrict__ postab,
    int relu)
{
    __shared__ float As[16 * 132];
    __shared__ float Bs[16 * 132];
    int m0 = blockIdx.x * 128, n0 = blockIdx.y * 128;
    int tid = threadIdx.x;
    int tx = tid & 15, ty = tid >> 4;
    float acc[8][8];
#pragma unroll
    for (int i = 0; i < 8; ++i)
#pragma unroll
        for (int j = 0; j < 8; ++j) acc[i][j] = 0.f;

    for (int k0 = 0; k0 < K; k0 += 16) {
#pragma unroll
        for (int i = 0; i < 8; ++i) {             // A: 128 m x 16 k
            int idx = i * 256 + tid;
            int m = idx >> 4, kl = idx & 15;
            int r = m0 + m, k = k0 + kl;
            As[kl * 132 + m] = (r < M && k < K) ? A[(long)r * K + k] : 0.f;
        }
#pragma unroll
        for (int i = 0; i < 8; ++i) {             // B: 16 k x 128 n
            int idx = i * 256 + tid;
            int n = idx & 127, k = idx >> 7;
            int kk = k0 + k, nn = n0 + n;
            Bs[k * 132 + n] = (kk < K && nn < N) ? Bm[(long)kk * N + nn] : 0.f;
        }
        __syncthreads();
#pragma unroll
        for (int kk = 0; kk < 16; ++kk) {
            float4 a0 = *(const float4*)&As[kk * 132 + ty * 4];
            float4 a1 = *(const float4*)&As[kk * 132 + 64 + ty * 4];
            float4 b0 = *(const float4*)&Bs[kk * 132 + tx * 4];
            float4 b1 = *(const float4*)&Bs[kk * 132 + 64 + tx * 4];
            float a[8] = {a0.x, a0.y, a0.z, a0.w, a1.x, a1.y, a1.z, a1.w};
            float b[8] = {b0.x, b0.y, b0.z, b0.w, b1.x, b1.y, b1.z, b1.w};
#pragma unroll
            for (int i = 0; i < 8; ++i)
#pragma unroll
                for (int j = 0; j < 8; ++j) acc[i][j] += a[i] * b[j];
        }
        __syncthreads();
    }
#pragma unroll
    for (int i = 0; i < 8; ++i) {
        int m = m0 + ((i < 4) ? (ty * 4 + i) : (64 + ty * 4 + i - 4));
        if (m >= M) continue;
#pragma unroll
        for (int j = 0; j < 8; ++j) {
            int n = n0 + ((j < 4) ? (tx * 4 + j) : (64 + tx * 4 + j - 4));
            if (n >= N) continue;
            float v = acc[i][j];
            if (bias) v += bias[n];
            if (res) v += res[(long)m * N + n];
            if (posidx) v += postab[(long)posidx[m] * N + n];
            if (relu) v = fmaxf(v, 0.f);
            C[(long)m * N + n] = v;
        }
    }
}

// ---------------------------------------------------------------------------
// LayerNorm over last dim N (=800), one block per row.
// ---------------------------------------------------------------------------
__global__ __launch_bounds__(256) void ln_f32(
    const float* __restrict__ X, float* __restrict__ Y,
    const float* __restrict__ g, const float* __restrict__ b, int N)
{
    int m = blockIdx.x;
    const float* x = X + (long)m * N;
    __shared__ float red[256];
    int tid = threadIdx.x;
    float s = 0.f;
    for (int i = tid; i < N; i += 256) s += x[i];
    red[tid] = s; __syncthreads();
    for (int o = 128; o > 0; o >>= 1) { if (tid < o) red[tid] += red[tid + o]; __syncthreads(); }
    float mean = red[0] / N;
    __syncthreads();
    float v = 0.f;
    for (int i = tid; i < N; i += 256) { float d = x[i] - mean; v += d * d; }
    red[tid] = v; __syncthreads();
    for (int o = 128; o > 0; o >>= 1) { if (tid < o) red[tid] += red[tid + o]; __syncthreads(); }
    float rs = rsqrtf(red[0] / N + 1e-6f);
    for (int i = tid; i < N; i += 256)
        Y[(long)m * N + i] = (x[i] - mean) * rs * g[i] + b[i];
}

// ---------------------------------------------------------------------------
// Fused banded attention (verified round 1).
// ---------------------------------------------------------------------------
__global__ __launch_bounds__(256) void attn_f32(
    const float* __restrict__ Q, const float* __restrict__ K,
    const float* __restrict__ V, float* __restrict__ O)
{
    int blk = blockIdx.x;
    int qt = blk & 127; int bh = blk >> 7;
    int h = bh & 7; int b = bh >> 3;
    int q0 = qt * 4;
    int tid = threadIdx.x;

    __shared__ float qv[4][DH_];
    __shared__ float sc[4][208];
    __shared__ float red[256];
    __shared__ float inv_den[4];

    for (int i = tid; i < 4 * DH_; i += 256) {
        int qi = i / DH_, d = i - qi * DH_;
        qv[qi][d] = Q[(long)(b * S_ + q0 + qi) * DM_ + h * DH_ + d];
    }
    __syncthreads();

    int w = tid;
    int k = q0 - WIN_ + w;
    bool kvalid = (w < 204) && (k >= 0) && (k < S_);
    float dots[4] = {0.f, 0.f, 0.f, 0.f};
    if (kvalid) {
        const float* krow = K + (long)(b * S_ + k) * DM_ + h * DH_;
        for (int d = 0; d < DH_; ++d) {
            float kvv = krow[d];
#pragma unroll
            for (int qi = 0; qi < 4; ++qi) dots[qi] += qv[qi][d] * kvv;
        }
    }
#pragma unroll
    for (int qi = 0; qi < 4; ++qi) {
        int wq = w - qi;
        if (w < 204 && wq >= 0 && wq < 201)
            sc[qi][wq] = kvalid ? dots[qi] * 0.1f : -1e30f;
    }
    __syncthreads();

    for (int qi = 0; qi < 4; ++qi) {
        float vmax = (tid < 201) ? sc[qi][tid] : -1e30f;
        red[tid] = vmax; __syncthreads();
        for (int o = 128; o > 0; o >>= 1) { if (tid < o) red[tid] = fmaxf(red[tid], red[tid + o]); __syncthreads(); }
        float mx = red[0];
        __syncthreads();
        float e = 0.f;
        if (tid < 201) { e = __expf(sc[qi][tid] - mx); sc[qi][tid] = e; }
        red[tid] = e; __syncthreads();
        for (int o = 128; o > 0; o >>= 1) { if (tid < o) red[tid] += red[tid + o]; __syncthreads(); }
        if (tid == 0) inv_den[qi] = 1.f / red[0];
        __syncthreads();
    }

    if (tid < DH_) {
        int d = tid;
        float o_[4] = {0.f, 0.f, 0.f, 0.f};
        for (int w2 = 0; w2 < 204; ++w2) {
            int k2 = q0 - WIN_ + w2;
            if (k2 < 0 || k2 >= S_) continue;
            float vv = V[(long)(b * S_ + k2) * DM_ + h * DH_ + d];
#pragma unroll
            for (int qi = 0; qi < 4; ++qi) {
                int wq = w2 - qi;
                if (wq >= 0 && wq < 201) o_[qi] += sc[qi][wq] * vv;
            }
        }
#pragma unroll
        for (int qi = 0; qi < 4; ++qi)
            O[(long)(b * S_ + q0 + qi) * DM_ + h * DH_ + d] = o_[qi] * inv_den[qi];
    }
}

// g3[j] = out_b @ Wx
__global__ __launch_bounds__(256) void g3_kernel(
    const float* __restrict__ outb, const float* __restrict__ Wx, float* __restrict__ g3)
{
    int j = blockIdx.x * 256 + threadIdx.x;
    if (j >= G4_) return;
    float s = 0.f;
    for (int p = 0; p < POSE_; ++p) s += outb[p] * Wx[(long)p * G4_ + j];
    g3[j] = s;
}

// init h state (TRANSPOSED: hT[hid][16]) + zero grid-barrier counters
__global__ __launch_bounds__(256) void init_state(
    const float* __restrict__ vh, float* __restrict__ h0T,
    unsigned* __restrict__ bar)
{
    int i = blockIdx.x * 256 + threadIdx.x;
    if (i < B_ * HID_) {
        int bb = i >> 10, hid = i & 1023;
        h0T[hid * 16 + bb] = vh[i];
    }
    if (i < 1088) bar[i] = 0u;
}

// ---------------------------------------------------------------------------
// tr_cat: WT[c][k] = (k<K1 ? in1[k][c] : k<K1+K2 ? in2[k-K1][c] : 0)
// ---------------------------------------------------------------------------
__global__ __launch_bounds__(256) void tr_cat(
    const float* __restrict__ in1, const float* __restrict__ in2,
    float* __restrict__ WT, int K1, int K2, int KP)
{
    __shared__ float tile[64][65];
    int k0 = blockIdx.x * 64, c0 = blockIdx.y * 64;
    int tid = threadIdx.x;
    int cl = tid & 63, kr = tid >> 6;
#pragma unroll
    for (int i = 0; i < 16; ++i) {
        int kl = i * 4 + kr;
        int k = k0 + kl, c = c0 + cl;
        float v = 0.f;
        if (k < K1) v = in1[(long)k * G4_ + c];
        else if (k < K1 + K2) v = in2[(long)(k - K1) * G4_ + c];
        tile[kl][cl] = v;
    }
    __syncthreads();
    int kl2 = tid & 63, cr = tid >> 6;
#pragma unroll
    for (int i = 0; i < 16; ++i) {
        int ci = i * 4 + cr;
        WT[(long)(c0 + ci) * KP + k0 + kl2] = tile[kl2][ci];
    }
}

// ---------------------------------------------------------------------------
// Fence-free two-level grid barrier. Arrivals: relaxed agent atomic RMW
// (544/step total -- cheap). Poll: PLAIN sc0/sc1 load (no RMW; round 2's
// atomic-load poll was part of the 219 GB storm). No cache maintenance ever.
// Ordering: wave 0's vmcnt(0) (from __syncthreads) covers the sc0/sc1 h
// stores (issued by lanes<32 of wave 0) before tid 0 arrives; readers pick
// h up at the MALL via sc0/sc1 loads.
// ---------------------------------------------------------------------------
__device__ __forceinline__ void grid_sync(unsigned* __restrict__ gcnt,
                                          unsigned* __restrict__ root,
                                          unsigned* __restrict__ gen, int step)
{
    __syncthreads();                       // vmcnt(0): h stores committed
    if (threadIdx.x == 0) {
        asm volatile("s_waitcnt vmcnt(0)" ::: "memory");
        unsigned grp = (unsigned)blockIdx.x >> 4;           // 32 groups x 16 blk
        unsigned tk = __hip_atomic_fetch_add(&gcnt[grp * 32], 1u,
                          __ATOMIC_RELAXED, __HIP_MEMORY_SCOPE_AGENT);
        if (tk == (unsigned)(16 * step + 15)) {             // last in group
            unsigned r = __hip_atomic_fetch_add(root, 1u,
                             __ATOMIC_RELAXED, __HIP_MEMORY_SCOPE_AGENT);
            if (r == (unsigned)(32 * step + 31))            // last group
                __hip_atomic_store(gen, (unsigned)(step + 1),
                    __ATOMIC_RELAXED, __HIP_MEMORY_SCOPE_AGENT);
        }
        while (ld_coh_u32(gen) <= (unsigned)step)
            __builtin_amdgcn_s_sleep(8);
    }
    __syncthreads();
}

// ---------------------------------------------------------------------------
// lstm_scan v3: persistent, weights-in-LDS, COALESCED coherent h exchange.
// - h buffers are transposed hT[1024][16]: staging thread tid reads 64
//   CONTIGUOUS bytes (one asm batch: 4x global_load_dwordx4 sc0 sc1, one
//   vmcnt) -> wave covers 4 KB contiguous at the MALL. Zero atomic RMW.
// - h written by 32 lanes via global_store_dword sc0 sc1 (write-through,
//   device-coherent); c-state in registers; WT_A in LDS (A-steps: zero
//   global weight traffic); WT_B/tgt/ENC normal cached loads (read-only,
//   L2 stays valid -- no invalidates anywhere).
// - pan content and FMA order bit-identical to the verified lstm_step3.
// LDS 60.4 KB -> 2 blocks/CU; 512 blocks co-resident on 256 CUs.
// ---------------------------------------------------------------------------
__global__ __launch_bounds__(256, 2) void lstm_scan(
    float* __restrict__ HB0T, float* __restrict__ HB1T,
    const float* __restrict__ vec_c,
    const float* __restrict__ WT_A, const float* __restrict__ WT_B,
    const float* __restrict__ g3, const float* __restrict__ lstm_b,
    const int* __restrict__ epoch,
    const float* __restrict__ tgt, const float* __restrict__ dec0,
    const float* __restrict__ ENC, float* __restrict__ Hall,
    unsigned* __restrict__ bar)
{
    __shared__ float WL[WLSZ_];       // 8 WT_A rows, stride WLS_
    __shared__ float pan[256 * 17];   // panel; reused as red[0..2303], gst[2304..]
    float* red = pan;
    float* gst = pan + 2304;

    int tid = threadIdx.x;
    int hid0 = blockIdx.x * 2;
    int kq = tid >> 4, b = tid & 15;
    int b3 = tid >> 1, hh = tid & 1;
    int p = (int)((double)epoch[0] * 0.01);   // match python int(epoch*LAMB)
    int per = p + 10;
    unsigned* gcnt = bar;
    unsigned* root = bar + 1024;
    unsigned* gen  = bar + 1056;

    // ---- one-time: stage this block's 8 WT_A rows into LDS ----
#pragma unroll
    for (int c = 0; c < 8; ++c) {
        const float* src = WT_A + (long)((c >> 1) * 1024 + hid0 + (c & 1)) * KPA_;
        for (int i = tid * 4; i < WLS_; i += 1024)
            *(float4*)&WL[c * WLS_ + i] = *(const float4*)&src[i];
    }
    for (int i = 8 * WLS_ + tid; i < WLSZ_; i += 256) WL[i] = 0.f;  // NaN guard

    // ---- c-state in registers (lane tid<32 owns (b3, hid0+hh)) ----
    float c_reg = 0.f;
    if (tid < 32) c_reg = vec_c[b3 * HID_ + hid0 + hh];
    __syncthreads();

    for (int t = 0; t < S_; ++t) {
        bool msk = (t % per) >= p;
        bool useA = msk || (t == 0);
        const float* hreadT = (t & 1) ? HB1T : HB0T;
        float*       hwT    = (t & 1) ? HB0T : HB1T;

        float acc[8] = {0.f, 0.f, 0.f, 0.f, 0.f, 0.f, 0.f, 0.f};

        if (useA) {
            for (int P = 0; P < KPA_; P += 256) {
                if (P < 1024) {
                    float4 v0, v1, v2, v3;
                    ldh16(hreadT + (long)(P + tid) * 16, v0, v1, v2, v3);
                    float* pp = &pan[tid * 17];
                    pp[0]=v0.x;  pp[1]=v0.y;  pp[2]=v0.z;  pp[3]=v0.w;
                    pp[4]=v1.x;  pp[5]=v1.y;  pp[6]=v1.z;  pp[7]=v1.w;
                    pp[8]=v2.x;  pp[9]=v2.y;  pp[10]=v2.z; pp[11]=v2.w;
                    pp[12]=v3.x; pp[13]=v3.y; pp[14]=v3.z; pp[15]=v3.w;
                } else {
                    int kx = P - 1024 + tid;
#pragma unroll
                    for (int bb = 0; bb < 16; ++bb) {
                        float v = 0.f;
                        if (kx < POSE_)
                            v = msk ? tgt[((long)bb * S_ + t) * POSE_ + kx]
                                    : dec0[bb * POSE_ + kx];
                        pan[tid * 17 + bb] = v;
                    }
                }
                __syncthreads();
                int kb = P + kq * 16;
#pragma unroll
                for (int j4 = 0; j4 < 4; ++j4) {
                    float4 w[8];
#pragma unroll
                    for (int c = 0; c < 8; ++c)
                        w[c] = *(const float4*)&WL[c * WLS_ + kb + j4 * 4];
                    float h0 = pan[(kq * 16 + j4 * 4 + 0) * 17 + b];
                    float h1 = pan[(kq * 16 + j4 * 4 + 1) * 17 + b];
                    float h2 = pan[(kq * 16 + j4 * 4 + 2) * 17 + b];
                    float h3 = pan[(kq * 16 + j4 * 4 + 3) * 17 + b];
#pragma unroll
                    for (int c = 0; c < 8; ++c)
                        acc[c] += w[c].x * h0 + w[c].y * h1 + w[c].z * h2 + w[c].w * h3;
                }
                __syncthreads();
            }
        } else {
            const float* wrow[8];
#pragma unroll
            for (int c = 0; c < 8; ++c)
                wrow[c] = WT_B + (long)((c >> 1) * 1024 + hid0 + (c & 1)) * KPB_;
            for (int P = 0; P < KPB_; P += 256) {
                if (P < 1024) {
                    float4 v0, v1, v2, v3;
                    ldh16(hreadT + (long)(P + tid) * 16, v0, v1, v2, v3);
                    float* pp = &pan[tid * 17];
                    pp[0]=v0.x;  pp[1]=v0.y;  pp[2]=v0.z;  pp[3]=v0.w;
                    pp[4]=v1.x;  pp[5]=v1.y;  pp[6]=v1.z;  pp[7]=v1.w;
                    pp[8]=v2.x;  pp[9]=v2.y;  pp[10]=v2.z; pp[11]=v2.w;
                    pp[12]=v3.x; pp[13]=v3.y; pp[14]=v3.z; pp[15]=v3.w;
                } else {
                    int kx = P - 1024 + tid;
#pragma unroll
                    for (int bb = 0; bb < 16; ++bb) {
                        float v = 0.f;
                        if (kx < DM_)
                            v = ENC[((long)bb * S_ + (t - 1)) * DM_ + kx];
                        pan[tid * 17 + bb] = v;
                    }
                }
                __syncthreads();
                int kb = P + kq * 16;
#pragma unroll
                for (int j4 = 0; j4 < 4; ++j4) {
                    float4 w[8];
#pragma unroll
                    for (int c = 0; c < 8; ++c)
                        w[c] = *(const float4*)(wrow[c] + kb + j4 * 4);
                    float h0 = pan[(kq * 16 + j4 * 4 + 0) * 17 + b];
                    float h1 = pan[(kq * 16 + j4 * 4 + 1) * 17 + b];
                    float h2 = pan[(kq * 16 + j4 * 4 + 2) * 17 + b];
                    float h3 = pan[(kq * 16 + j4 * 4 + 3) * 17 + b];
#pragma unroll
                    for (int c = 0; c < 8; ++c)
                        acc[c] += w[c].x * h0 + w[c].y * h1 + w[c].z * h2 + w[c].w * h3;
                }
                __syncthreads();
            }
        }

        // ---- reduce 16 k-slices (pan dead; red aliases it) ----
#pragma unroll
        for (int c = 0; c < 8; ++c) red[(b * 16 + kq) * 9 + c] = acc[c];
        __syncthreads();

        if (tid < 128) {
            int ob = tid >> 3, oc = tid & 7;
            float s = 0.f;
#pragma unroll
            for (int q = 0; q < 16; ++q) s += red[(ob * 16 + q) * 9 + oc];
            int gcol = (oc >> 1) * 1024 + hid0 + (oc & 1);
            s += lstm_b[gcol];
            if (!useA) s += g3[gcol];
            gst[oc * 16 + ob] = s;
        }
        __syncthreads();

        if (tid < 32) {
            int hid = hid0 + hh;
            float iv = gst[(0 * 2 + hh) * 16 + b3];
            float fv = gst[(1 * 2 + hh) * 16 + b3];
            float gv = gst[(2 * 2 + hh) * 16 + b3];
            float ov = gst[(3 * 2 + hh) * 16 + b3];
            float ig = 1.f / (1.f + __expf(-iv));
            float fg = 1.f / (1.f + __expf(-fv));
            float og = 1.f / (1.f + __expf(-ov));
            float cn = fg * c_reg + ig * tanhf(gv);
            float hn = og * tanhf(cn);
            c_reg = cn;
            st_coh(&hwT[hid * 16 + b3], hn);               // coherent, coalesced
            Hall[((long)b3 * S_ + t) * HID_ + hid] = hn;   // normal store
        }

        grid_sync(gcnt, root, gen, t);
    }
}

// ---------------------------------------------------------------------------
extern "C" void kernel_launch(void* const* d_in, const int* in_sizes, int n_in,
                              void* d_out, int out_size, void* d_ws, size_t ws_size,
                              hipStream_t stream) {
    const float* src_seq  = (const float*)d_in[0];
    const int*   src_pos  = (const int*)  d_in[1];
    const float* tgt_seq  = (const float*)d_in[2];
    const float* vec_h    = (const float*)d_in[3];
    const float* vec_c    = (const float*)d_in[4];
    const float* dec0     = (const float*)d_in[5];
    const float* emb_W    = (const float*)d_in[6];
    const float* emb_b    = (const float*)d_in[7];
    const float* pos_tab  = (const float*)d_in[8];
    const float* Wq       = (const float*)d_in[9];
    const float* Wk       = (const float*)d_in[10];
    const float* Wv       = (const float*)d_in[11];
    const float* Wo       = (const float*)d_in[12];
    const float* ln1_g    = (const float*)d_in[13];
    const float* ln1_b    = (const float*)d_in[14];
    const float* ffn_W1   = (const float*)d_in[15];
    const float* ffn_b1   = (const float*)d_in[16];
    const float* ffn_W2   = (const float*)d_in[17];
    const float* ffn_b2   = (const float*)d_in[18];
    const float* ln2_g    = (const float*)d_in[19];
    const float* ln2_b    = (const float*)d_in[20];
    const float* lstm_Wx  = (const float*)d_in[21];
    const float* lstm_Wh  = (const float*)d_in[22];
    const float* lstm_b   = (const float*)d_in[23];
    const float* out_W    = (const float*)d_in[24];
    const float* out_b    = (const float*)d_in[25];
    const int*   epoch    = (const int*)  d_in[26];

    // ---- workspace layout (total 41,209,856 floats = 164.8 MB) ----
    float* ws = (float*)d_ws;
    const long NX = (long)B_ * S_ * DM_;           // 6,553,600
    float* X      = ws;                            // enc / residual [0, NX)
    float* R      = X + NX;                        // 34,603,008-float region
    // encoder phase:
    float* Qb     = R;
    float* Kb     = Qb + NX;
    float* Vb     = Kb + NX;
    float* Ob     = Vb + NX;
    float* FFNH   = Ob + NX;                       // 8,388,608
    // decoder phase (aliases into R; encoder scratch dead):
    float* WEFF_t = R;                             // 4,194,304
    float* G2     = R + 4194304;                   // 3,276,800 (dead after tr_cat B)
    float* WT_A   = R + 7471104;                   // 6,291,456 (4096 x 1536)
    float* WT_B   = R + 13762560;                  // 8,388,608 (4096 x 2048)
    float* Hall   = R + 22151168;                  // 8,388,608 (B*S x 1024)
    float* T1     = WEFF_t;                        // 2,244,608 (after WT_B built)
    float* TAIL   = R + 34603008;
    float* G3v    = TAIL;                          // 4096
    float* HB0T   = G3v + G4_;                     // 16384 (transposed [1024][16])
    float* HB1T   = HB0T + B_ * HID_;
    // barrier counters live in the dead G2 region (zeroed after tr_cat B)
    unsigned* BAR = (unsigned*)G2;                 // 1088 uints

    const int M = B_ * S_; // 8192
    dim3 blk(256);

    // ---- encoder ----
    gemm128<<<dim3(M / 128, (DM_ + 127) / 128), blk, 0, stream>>>(
        src_seq, emb_W, X, M, DM_, FRAME_, emb_b, nullptr, src_pos, pos_tab, 0);
    gemm128<<<dim3(M / 128, (DM_ + 127) / 128), blk, 0, stream>>>(
        X, Wq, Qb, M, DM_, DM_, nullptr, nullptr, nullptr, nullptr, 0);
    gemm128<<<dim3(M / 128, (DM_ + 127) / 128), blk, 0, stream>>>(
        X, Wk, Kb, M, DM_, DM_, nullptr, nullptr, nullptr, nullptr, 0);
    gemm128<<<dim3(M / 128, (DM_ + 127) / 128), blk, 0, stream>>>(
        X, Wv, Vb, M, DM_, DM_, nullptr, nullptr, nullptr, nullptr, 0);
    attn_f32<<<dim3(B_ * H_ * (S_ / 4)), blk, 0, stream>>>(Qb, Kb, Vb, Ob);
    gemm128<<<dim3(M / 128, (DM_ + 127) / 128), blk, 0, stream>>>(
        Ob, Wo, FFNH, M, DM_, DM_, nullptr, X, nullptr, nullptr, 0);
    ln_f32<<<dim3(M), blk, 0, stream>>>(FFNH, X, ln1_g, ln1_b, DM_);
    gemm128<<<dim3(M / 128, FFN_ / 128), blk, 0, stream>>>(
        X, ffn_W1, FFNH, M, FFN_, DM_, ffn_b1, nullptr, nullptr, nullptr, 1);
    gemm128<<<dim3(M / 128, (DM_ + 127) / 128), blk, 0, stream>>>(
        FFNH, ffn_W2, Ob, M, DM_, FFN_, ffn_b2, X, nullptr, nullptr, 0);
    ln_f32<<<dim3(M), blk, 0, stream>>>(Ob, X, ln2_g, ln2_b, DM_);   // X = enc

    // ---- decoder precompute ----
    // WEFF_t = out_W[:1024]@lstm_Wx + lstm_Wh   (1024 x 4096)
    gemm128<<<dim3(HID_ / 128, G4_ / 128), blk, 0, stream>>>(
        out_W, lstm_Wx, WEFF_t, HID_, G4_, POSE_, nullptr, lstm_Wh, nullptr, nullptr, 0);
    // G2 = out_W[1024:]@lstm_Wx   (800 x 4096)
    gemm128<<<dim3((DM_ + 127) / 128, G4_ / 128), blk, 0, stream>>>(
        out_W + (long)HID_ * POSE_, lstm_Wx, G2, DM_, G4_, POSE_,
        nullptr, nullptr, nullptr, nullptr, 0);
    // transposed, zero-padded step weights
    tr_cat<<<dim3(KPA_ / 64, G4_ / 64), blk, 0, stream>>>(
        lstm_Wh, lstm_Wx, WT_A, HID_, POSE_, KPA_);
    tr_cat<<<dim3(KPB_ / 64, G4_ / 64), blk, 0, stream>>>(
        WEFF_t, G2, WT_B, HID_, DM_, KPB_);
    g3_kernel<<<dim3(G4_ / 256), blk, 0, stream>>>(out_b, lstm_Wx, G3v);
    // init hT (transposed) + zero barrier counters (G2 is dead by now)
    init_state<<<dim3((B_ * HID_ + 255) / 256), blk, 0, stream>>>(
        vec_h, HB0T, BAR);
    // T1 = enc@out_W[1024:,:] + out_b  (aliases WEFF_t -> must follow tr_cat)
    gemm128<<<dim3(M / 128, (POSE_ + 127) / 128), blk, 0, stream>>>(
        X, out_W + (long)HID_ * POSE_, T1, M, POSE_, DM_, out_b,
        nullptr, nullptr, nullptr, 0);

    // ---- fused sequential scan: persistent kernel, coherent h exchange ----
    lstm_scan<<<dim3(NBLK_SCAN), blk, 0, stream>>>(
        HB0T, HB1T, vec_c, WT_A, WT_B, G3v, lstm_b, epoch,
        tgt_seq, dec0, X, Hall, BAR);

    // ---- final: out = Hall@out_W[:1024] + T1 ----
    gemm128<<<dim3(M / 128, (POSE_ + 127) / 128), blk, 0, stream>>>(
        Hall, out_W, (float*)d_out, M, POSE_, HID_, nullptr, T1,
        nullptr, nullptr, 0);
}

// Round 5
// 15710.890 us; speedup vs baseline: 5.9063x; 4.9303x over previous
//
#include <hip/hip_runtime.h>
#include <math.h>

#define B_ 16
#define S_ 512
#define FRAME_ 438
#define DM_ 800
#define H_ 8
#define DH_ 100
#define FFN_ 1024
#define HID_ 1024
#define POSE_ 274
#define WIN_ 100
#define G4_ 4096     // 4*HID
#define KPA_ 1536    // padded K for WT_A ([Wh;Wx], K=1298)
#define KPB_ 2048    // padded K for WT_B ([WEFF;G2], K=1824)
#define NBLK_SCAN 512
#define WLS_ 1312    // LDS row stride for WT_A slice (>=1298, mult of 4)
#define WLSZ_ (8 * WLS_ + 256)  // + zero tail: last row reads up to WLS_+223 past

// h-ring: 513 slots x 16384 floats (64 KB), carved from scan-dead ws regions.
// Slot n holds h after step n-1 (n=0 = initial h). Addresses are used ONCE:
// written (sc0/sc1 -> MALL) at step n-1, read (normal cached) at step n.
// No XCD L2 can hold a stale copy of an address it has never accessed, and
// the scan kernel's launch acquire invalidated everything older.
#define RING_SLOT_F 16384L

// ---------------------------------------------------------------------------
// Coherent (MALL-point) helpers. sc0 sc1 = bypass L1/L2, serve at LLC.
// Round 2/3 lesson: NEVER move bulk data this way (512-way MALL fan-out,
// 5-40x slowdowns). Used ONLY for: h writes (2 lines/block/step), barrier
// gen lines. Bulk reads go through normal cached loads on fresh addresses.
// ---------------------------------------------------------------------------
__device__ __forceinline__ void st_coh(float* p, float v)
{
    asm volatile("global_store_dword %0, %1, off sc0 sc1"
                 :: "v"(p), "v"(v) : "memory");
}

__device__ __forceinline__ void st_coh_u32(unsigned* p, unsigned v)
{
    asm volatile("global_store_dword %0, %1, off sc0 sc1"
                 :: "v"(p), "v"(v) : "memory");
}

__device__ __forceinline__ unsigned ld_coh_u32(const unsigned* p)
{
    unsigned v;
    asm volatile("global_load_dword %0, %1, off sc0 sc1\n\t"
                 "s_waitcnt vmcnt(0)"
                 : "=v"(v) : "v"(p) : "memory");
    return v;
}

__host__ __device__ __forceinline__ float* ring_slot(float* R, int n)
{
    long off;
    if (n < 248)      off = 30539776L + (long)n * RING_SLOT_F;        // Hall..TAIL gap
    else if (n < 447) off = 4210688L + (long)(n - 248) * RING_SLOT_F; // dead G2 (past BAR)
    else              off = 2244608L + (long)(n - 447) * RING_SLOT_F; // dead T1 tail
    return R + off;
}

// ---------------------------------------------------------------------------
// gemm128: fp32, 128x128 tile, 256 thr, 8x8 micro (split 4+4, conflict-free
// LDS). C = A@B (+bias[N]) (+res[M,N]) (+pos_table[posidx[m]]) (relu).
// ---------------------------------------------------------------------------
__global__ __launch_bounds__(256) void gemm128(
    const float* __restrict__ A, const float* __restrict__ Bm,
    float* __restrict__ C, int M, int N, int K,
    const float* __restrict__ bias, const float* __restrict__ res,
    const int* __restrict__ posidx, const float* __restrict__ postab,
    int relu)
{
    __shared__ float As[16 * 132];
    __shared__ float Bs[16 * 132];
    int m0 = blockIdx.x * 128, n0 = blockIdx.y * 128;
    int tid = threadIdx.x;
    int tx = tid & 15, ty = tid >> 4;
    float acc[8][8];
#pragma unroll
    for (int i = 0; i < 8; ++i)
#pragma unroll
        for (int j = 0; j < 8; ++j) acc[i][j] = 0.f;

    for (int k0 = 0; k0 < K; k0 += 16) {
#pragma unroll
        for (int i = 0; i < 8; ++i) {             // A: 128 m x 16 k
            int idx = i * 256 + tid;
            int m = idx >> 4, kl = idx & 15;
            int r = m0 + m, k = k0 + kl;
            As[kl * 132 + m] = (r < M && k < K) ? A[(long)r * K + k] : 0.f;
        }
#pragma unroll
        for (int i = 0; i < 8; ++i) {             // B: 16 k x 128 n
            int idx = i * 256 + tid;
            int n = idx & 127, k = idx >> 7;
            int kk = k0 + k, nn = n0 + n;
            Bs[k * 132 + n] = (kk < K && nn < N) ? Bm[(long)kk * N + nn] : 0.f;
        }
        __syncthreads();
#pragma unroll
        for (int kk = 0; kk < 16; ++kk) {
            float4 a0 = *(const float4*)&As[kk * 132 + ty * 4];
            float4 a1 = *(const float4*)&As[kk * 132 + 64 + ty * 4];
            float4 b0 = *(const float4*)&Bs[kk * 132 + tx * 4];
            float4 b1 = *(const float4*)&Bs[kk * 132 + 64 + tx * 4];
            float a[8] = {a0.x, a0.y, a0.z, a0.w, a1.x, a1.y, a1.z, a1.w};
            float b[8] = {b0.x, b0.y, b0.z, b0.w, b1.x, b1.y, b1.z, b1.w};
#pragma unroll
            for (int i = 0; i < 8; ++i)
#pragma unroll
                for (int j = 0; j < 8; ++j) acc[i][j] += a[i] * b[j];
        }
        __syncthreads();
    }
#pragma unroll
    for (int i = 0; i < 8; ++i) {
        int m = m0 + ((i < 4) ? (ty * 4 + i) : (64 + ty * 4 + i - 4));
        if (m >= M) continue;
#pragma unroll
        for (int j = 0; j < 8; ++j) {
            int n = n0 + ((j < 4) ? (tx * 4 + j) : (64 + tx * 4 + j - 4));
            if (n >= N) continue;
            float v = acc[i][j];
            if (bias) v += bias[n];
            if (res) v += res[(long)m * N + n];
            if (posidx) v += postab[(long)posidx[m] * N + n];
            if (relu) v = fmaxf(v, 0.f);
            C[(long)m * N + n] = v;
        }
    }
}

// ---------------------------------------------------------------------------
// LayerNorm over last dim N (=800), one block per row.
// ---------------------------------------------------------------------------
__global__ __launch_bounds__(256) void ln_f32(
    const float* __restrict__ X, float* __restrict__ Y,
    const float* __restrict__ g, const float* __restrict__ b, int N)
{
    int m = blockIdx.x;
    const float* x = X + (long)m * N;
    __shared__ float red[256];
    int tid = threadIdx.x;
    float s = 0.f;
    for (int i = tid; i < N; i += 256) s += x[i];
    red[tid] = s; __syncthreads();
    for (int o = 128; o > 0; o >>= 1) { if (tid < o) red[tid] += red[tid + o]; __syncthreads(); }
    float mean = red[0] / N;
    __syncthreads();
    float v = 0.f;
    for (int i = tid; i < N; i += 256) { float d = x[i] - mean; v += d * d; }
    red[tid] = v; __syncthreads();
    for (int o = 128; o > 0; o >>= 1) { if (tid < o) red[tid] += red[tid + o]; __syncthreads(); }
    float rs = rsqrtf(red[0] / N + 1e-6f);
    for (int i = tid; i < N; i += 256)
        Y[(long)m * N + i] = (x[i] - mean) * rs * g[i] + b[i];
}

// ---------------------------------------------------------------------------
// Fused banded attention (verified round 1).
// ---------------------------------------------------------------------------
__global__ __launch_bounds__(256) void attn_f32(
    const float* __restrict__ Q, const float* __restrict__ K,
    const float* __restrict__ V, float* __restrict__ O)
{
    int blk = blockIdx.x;
    int qt = blk & 127; int bh = blk >> 7;
    int h = bh & 7; int b = bh >> 3;
    int q0 = qt * 4;
    int tid = threadIdx.x;

    __shared__ float qv[4][DH_];
    __shared__ float sc[4][208];
    __shared__ float red[256];
    __shared__ float inv_den[4];

    for (int i = tid; i < 4 * DH_; i += 256) {
        int qi = i / DH_, d = i - qi * DH_;
        qv[qi][d] = Q[(long)(b * S_ + q0 + qi) * DM_ + h * DH_ + d];
    }
    __syncthreads();

    int w = tid;
    int k = q0 - WIN_ + w;
    bool kvalid = (w < 204) && (k >= 0) && (k < S_);
    float dots[4] = {0.f, 0.f, 0.f, 0.f};
    if (kvalid) {
        const float* krow = K + (long)(b * S_ + k) * DM_ + h * DH_;
        for (int d = 0; d < DH_; ++d) {
            float kvv = krow[d];
#pragma unroll
            for (int qi = 0; qi < 4; ++qi) dots[qi] += qv[qi][d] * kvv;
        }
    }
#pragma unroll
    for (int qi = 0; qi < 4; ++qi) {
        int wq = w - qi;
        if (w < 204 && wq >= 0 && wq < 201)
            sc[qi][wq] = kvalid ? dots[qi] * 0.1f : -1e30f;
    }
    __syncthreads();

    for (int qi = 0; qi < 4; ++qi) {
        float vmax = (tid < 201) ? sc[qi][tid] : -1e30f;
        red[tid] = vmax; __syncthreads();
        for (int o = 128; o > 0; o >>= 1) { if (tid < o) red[tid] = fmaxf(red[tid], red[tid + o]); __syncthreads(); }
        float mx = red[0];
        __syncthreads();
        float e = 0.f;
        if (tid < 201) { e = __expf(sc[qi][tid] - mx); sc[qi][tid] = e; }
        red[tid] = e; __syncthreads();
        for (int o = 128; o > 0; o >>= 1) { if (tid < o) red[tid] += red[tid + o]; __syncthreads(); }
        if (tid == 0) inv_den[qi] = 1.f / red[0];
        __syncthreads();
    }

    if (tid < DH_) {
        int d = tid;
        float o_[4] = {0.f, 0.f, 0.f, 0.f};
        for (int w2 = 0; w2 < 204; ++w2) {
            int k2 = q0 - WIN_ + w2;
            if (k2 < 0 || k2 >= S_) continue;
            float vv = V[(long)(b * S_ + k2) * DM_ + h * DH_ + d];
#pragma unroll
            for (int qi = 0; qi < 4; ++qi) {
                int wq = w2 - qi;
                if (wq >= 0 && wq < 201) o_[qi] += sc[qi][wq] * vv;
            }
        }
#pragma unroll
        for (int qi = 0; qi < 4; ++qi)
            O[(long)(b * S_ + q0 + qi) * DM_ + h * DH_ + d] = o_[qi] * inv_den[qi];
    }
}

// g3[j] = out_b @ Wx
__global__ __launch_bounds__(256) void g3_kernel(
    const float* __restrict__ outb, const float* __restrict__ Wx, float* __restrict__ g3)
{
    int j = blockIdx.x * 256 + threadIdx.x;
    if (j >= G4_) return;
    float s = 0.f;
    for (int p = 0; p < POSE_; ++p) s += outb[p] * Wx[(long)p * G4_ + j];
    g3[j] = s;
}

// init h state into ring slot 0 (TRANSPOSED: [hid][16]) + zero barrier state
__global__ __launch_bounds__(256) void init_state(
    const float* __restrict__ vh, float* __restrict__ ring0,
    unsigned* __restrict__ bar)
{
    int i = blockIdx.x * 256 + threadIdx.x;
    if (i < B_ * HID_) {
        int bb = i >> 10, hid = i & 1023;
        ring0[hid * 16 + bb] = vh[i];
    }
    if (i < 2080) bar[i] = 0u;
}

// ---------------------------------------------------------------------------
// tr_cat: WT[c][k] = (k<K1 ? in1[k][c] : k<K1+K2 ? in2[k-K1][c] : 0)
// ---------------------------------------------------------------------------
__global__ __launch_bounds__(256) void tr_cat(
    const float* __restrict__ in1, const float* __restrict__ in2,
    float* __restrict__ WT, int K1, int K2, int KP)
{
    __shared__ float tile[64][65];
    int k0 = blockIdx.x * 64, c0 = blockIdx.y * 64;
    int tid = threadIdx.x;
    int cl = tid & 63, kr = tid >> 6;
#pragma unroll
    for (int i = 0; i < 16; ++i) {
        int kl = i * 4 + kr;
        int k = k0 + kl, c = c0 + cl;
        float v = 0.f;
        if (k < K1) v = in1[(long)k * G4_ + c];
        else if (k < K1 + K2) v = in2[(long)(k - K1) * G4_ + c];
        tile[kl][cl] = v;
    }
    __syncthreads();
    int kl2 = tid & 63, cr = tid >> 6;
#pragma unroll
    for (int i = 0; i < 16; ++i) {
        int ci = i * 4 + cr;
        WT[(long)(c0 + ci) * KP + k0 + kl2] = tile[kl2][ci];
    }
}

// ---------------------------------------------------------------------------
// Fence-free two-level grid barrier. Arrivals: relaxed agent atomic RMW on
// 32 group lines + 1 root line (proven correct rounds 1-3). Release: root
// writes 32 REPLICATED gen lines (sc0/sc1) so only 16 blocks poll each line.
// No cache maintenance ever; data coherence comes from the fresh-address
// ring, not from this barrier.
// ---------------------------------------------------------------------------
__device__ __forceinline__ void grid_sync(unsigned* __restrict__ gcnt,
                                          unsigned* __restrict__ root,
                                          unsigned* __restrict__ genA, int step)
{
    __syncthreads();
    if (threadIdx.x == 0) {
        asm volatile("s_waitcnt vmcnt(0)" ::: "memory");    // h st_coh drained
        unsigned grp = (unsigned)blockIdx.x >> 4;           // 32 groups x 16 blk
        unsigned tk = __hip_atomic_fetch_add(&gcnt[grp * 32], 1u,
                          __ATOMIC_RELAXED, __HIP_MEMORY_SCOPE_AGENT);
        if (tk == (unsigned)(16 * step + 15)) {             // last in group
            unsigned r = __hip_atomic_fetch_add(root, 1u,
                             __ATOMIC_RELAXED, __HIP_MEMORY_SCOPE_AGENT);
            if (r == (unsigned)(32 * step + 31)) {          // last group
#pragma unroll
                for (int j = 0; j < 32; ++j)
                    st_coh_u32(&genA[j * 32], (unsigned)(step + 1));
            }
        }
        while (ld_coh_u32(&genA[grp * 32]) <= (unsigned)step)
            __builtin_amdgcn_s_sleep(16);
    }
    __syncthreads();
}

// ---------------------------------------------------------------------------
// lstm_scan v4: persistent; weights-in-LDS; h exchanged via FRESH-ADDRESS
// ring with NORMAL CACHED reads.
// - Step t: read h from ring(t) with plain float4 loads (L2 miss -> MALL ->
//   then 64 blocks/XCD share the L2 copy: the broadcast is absorbed by L2,
//   which rounds 2/3 proved is mandatory). Write h to ring(t+1) via sc0/sc1
//   stores (2 cache lines/block) so MALL has it before the barrier releases.
// - Stale lines impossible: each ring address is read exactly once, at the
//   step after its (write-through) write; launch acquire invalidated L2s.
// - WT_A in LDS (A-steps, 91%: zero global weight traffic); WT_B/tgt/ENC
//   normal cached reads; c-state in registers.
// - pan content and FMA order bit-identical to the verified lstm_step3.
// LDS 60.4 KB -> 2 blocks/CU; 512 blocks co-resident on 256 CUs.
// ---------------------------------------------------------------------------
__global__ __launch_bounds__(256, 2) void lstm_scan(
    float* __restrict__ Rbase,
    const float* __restrict__ vec_c,
    const float* __restrict__ WT_A, const float* __restrict__ WT_B,
    const float* __restrict__ g3, const float* __restrict__ lstm_b,
    const int* __restrict__ epoch,
    const float* __restrict__ tgt, const float* __restrict__ dec0,
    const float* __restrict__ ENC, float* __restrict__ Hall,
    unsigned* __restrict__ bar)
{
    __shared__ float WL[WLSZ_];       // 8 WT_A rows, stride WLS_
    __shared__ float pan[256 * 17];   // panel; reused as red[0..2303], gst[2304..]
    float* red = pan;
    float* gst = pan + 2304;

    int tid = threadIdx.x;
    int hid0 = blockIdx.x * 2;
    int kq = tid >> 4, b = tid & 15;
    int b3 = tid >> 1, hh = tid & 1;
    int p = (int)((double)epoch[0] * 0.01);   // match python int(epoch*LAMB)
    int per = p + 10;
    unsigned* gcnt = bar;
    unsigned* root = bar + 1024;
    unsigned* genA = bar + 1056;

    // ---- one-time: stage this block's 8 WT_A rows into LDS ----
#pragma unroll
    for (int c = 0; c < 8; ++c) {
        const float* src = WT_A + (long)((c >> 1) * 1024 + hid0 + (c & 1)) * KPA_;
        for (int i = tid * 4; i < WLS_; i += 1024)
            *(float4*)&WL[c * WLS_ + i] = *(const float4*)&src[i];
    }
    for (int i = 8 * WLS_ + tid; i < WLSZ_; i += 256) WL[i] = 0.f;  // NaN guard

    // ---- c-state in registers (lane tid<32 owns (b3, hid0+hh)) ----
    float c_reg = 0.f;
    if (tid < 32) c_reg = vec_c[b3 * HID_ + hid0 + hh];
    __syncthreads();

    for (int t = 0; t < S_; ++t) {
        bool msk = (t % per) >= p;
        bool useA = msk || (t == 0);
        const float* hrd = ring_slot(Rbase, t);       // fresh for this XCD
        float*       hwr = ring_slot(Rbase, t + 1);

        float acc[8] = {0.f, 0.f, 0.f, 0.f, 0.f, 0.f, 0.f, 0.f};

        // prefetch h-panel 0: thread tid owns row hid=tid, 64 contiguous bytes
        float4 h0v, h1v, h2v, h3v;
        {
            const float* q = hrd + (long)tid * 16;
            h0v = *(const float4*)(q);      h1v = *(const float4*)(q + 4);
            h2v = *(const float4*)(q + 8);  h3v = *(const float4*)(q + 12);
        }

        const int KP = useA ? KPA_ : KPB_;
        const float* wrow[8];
        if (!useA) {
#pragma unroll
            for (int c = 0; c < 8; ++c)
                wrow[c] = WT_B + (long)((c >> 1) * 1024 + hid0 + (c & 1)) * KPB_;
        }

        for (int P = 0; P < KP; P += 256) {
            if (P < 1024) {
                float* pp = &pan[tid * 17];
                pp[0]=h0v.x;  pp[1]=h0v.y;  pp[2]=h0v.z;  pp[3]=h0v.w;
                pp[4]=h1v.x;  pp[5]=h1v.y;  pp[6]=h1v.z;  pp[7]=h1v.w;
                pp[8]=h2v.x;  pp[9]=h2v.y;  pp[10]=h2v.z; pp[11]=h2v.w;
                pp[12]=h3v.x; pp[13]=h3v.y; pp[14]=h3v.z; pp[15]=h3v.w;
            } else {
                int kx = P - 1024 + tid;
                if (useA) {
#pragma unroll
                    for (int bb = 0; bb < 16; ++bb) {
                        float v = 0.f;
                        if (kx < POSE_)
                            v = msk ? tgt[((long)bb * S_ + t) * POSE_ + kx]
                                    : dec0[bb * POSE_ + kx];
                        pan[tid * 17 + bb] = v;
                    }
                } else {
#pragma unroll
                    for (int bb = 0; bb < 16; ++bb) {
                        float v = 0.f;
                        if (kx < DM_)
                            v = ENC[((long)bb * S_ + (t - 1)) * DM_ + kx];
                        pan[tid * 17 + bb] = v;
                    }
                }
            }
            __syncthreads();
            if (P + 256 < 1024) {              // prefetch next h-panel
                const float* q = hrd + (long)(P + 256 + tid) * 16;
                h0v = *(const float4*)(q);      h1v = *(const float4*)(q + 4);
                h2v = *(const float4*)(q + 8);  h3v = *(const float4*)(q + 12);
            }
            int kb = P + kq * 16;
            if (useA) {
#pragma unroll
                for (int j4 = 0; j4 < 4; ++j4) {
                    float4 w[8];
#pragma unroll
                    for (int c = 0; c < 8; ++c)
                        w[c] = *(const float4*)&WL[c * WLS_ + kb + j4 * 4];
                    float h0 = pan[(kq * 16 + j4 * 4 + 0) * 17 + b];
                    float h1 = pan[(kq * 16 + j4 * 4 + 1) * 17 + b];
                    float h2 = pan[(kq * 16 + j4 * 4 + 2) * 17 + b];
                    float h3 = pan[(kq * 16 + j4 * 4 + 3) * 17 + b];
#pragma unroll
                    for (int c = 0; c < 8; ++c)
                        acc[c] += w[c].x * h0 + w[c].y * h1 + w[c].z * h2 + w[c].w * h3;
                }
            } else {
#pragma unroll
                for (int j4 = 0; j4 < 4; ++j4) {
                    float4 w[8];
#pragma unroll
                    for (int c = 0; c < 8; ++c)
                        w[c] = *(const float4*)(wrow[c] + kb + j4 * 4);
                    float h0 = pan[(kq * 16 + j4 * 4 + 0) * 17 + b];
                    float h1 = pan[(kq * 16 + j4 * 4 + 1) * 17 + b];
                    float h2 = pan[(kq * 16 + j4 * 4 + 2) * 17 + b];
                    float h3 = pan[(kq * 16 + j4 * 4 + 3) * 17 + b];
#pragma unroll
                    for (int c = 0; c < 8; ++c)
                        acc[c] += w[c].x * h0 + w[c].y * h1 + w[c].z * h2 + w[c].w * h3;
                }
            }
            __syncthreads();
        }

        // ---- reduce 16 k-slices (pan dead; red aliases it) ----
#pragma unroll
        for (int c = 0; c < 8; ++c) red[(b * 16 + kq) * 9 + c] = acc[c];
        __syncthreads();

        if (tid < 128) {
            int ob = tid >> 3, oc = tid & 7;
            float s = 0.f;
#pragma unroll
            for (int q = 0; q < 16; ++q) s += red[(ob * 16 + q) * 9 + oc];
            int gcol = (oc >> 1) * 1024 + hid0 + (oc & 1);
            s += lstm_b[gcol];
            if (!useA) s += g3[gcol];
            gst[oc * 16 + ob] = s;
        }
        __syncthreads();

        if (tid < 32) {
            int hid = hid0 + hh;
            float iv = gst[(0 * 2 + hh) * 16 + b3];
            float fv = gst[(1 * 2 + hh) * 16 + b3];
            float gv = gst[(2 * 2 + hh) * 16 + b3];
            float ov = gst[(3 * 2 + hh) * 16 + b3];
            float ig = 1.f / (1.f + __expf(-iv));
            float fg = 1.f / (1.f + __expf(-fv));
            float og = 1.f / (1.f + __expf(-ov));
            float cn = fg * c_reg + ig * tanhf(gv);
            float hn = og * tanhf(cn);
            c_reg = cn;
            st_coh(&hwr[hid * 16 + b3], hn);               // write-through to MALL
            Hall[((long)b3 * S_ + t) * HID_ + hid] = hn;   // normal store
        }

        grid_sync(gcnt, root, genA, t);
    }
}

// ---------------------------------------------------------------------------
extern "C" void kernel_launch(void* const* d_in, const int* in_sizes, int n_in,
                              void* d_out, int out_size, void* d_ws, size_t ws_size,
                              hipStream_t stream) {
    const float* src_seq  = (const float*)d_in[0];
    const int*   src_pos  = (const int*)  d_in[1];
    const float* tgt_seq  = (const float*)d_in[2];
    const float* vec_h    = (const float*)d_in[3];
    const float* vec_c    = (const float*)d_in[4];
    const float* dec0     = (const float*)d_in[5];
    const float* emb_W    = (const float*)d_in[6];
    const float* emb_b    = (const float*)d_in[7];
    const float* pos_tab  = (const float*)d_in[8];
    const float* Wq       = (const float*)d_in[9];
    const float* Wk       = (const float*)d_in[10];
    const float* Wv       = (const float*)d_in[11];
    const float* Wo       = (const float*)d_in[12];
    const float* ln1_g    = (const float*)d_in[13];
    const float* ln1_b    = (const float*)d_in[14];
    const float* ffn_W1   = (const float*)d_in[15];
    const float* ffn_b1   = (const float*)d_in[16];
    const float* ffn_W2   = (const float*)d_in[17];
    const float* ffn_b2   = (const float*)d_in[18];
    const float* ln2_g    = (const float*)d_in[19];
    const float* ln2_b    = (const float*)d_in[20];
    const float* lstm_Wx  = (const float*)d_in[21];
    const float* lstm_Wh  = (const float*)d_in[22];
    const float* lstm_b   = (const float*)d_in[23];
    const float* out_W    = (const float*)d_in[24];
    const float* out_b    = (const float*)d_in[25];
    const int*   epoch    = (const int*)  d_in[26];

    // ---- workspace layout (total 41,209,856 floats = 164.8 MB) ----
    float* ws = (float*)d_ws;
    const long NX = (long)B_ * S_ * DM_;           // 6,553,600
    float* X      = ws;                            // enc / residual [0, NX)
    float* R      = X + NX;                        // 34,603,008-float region
    // encoder phase:
    float* Qb     = R;
    float* Kb     = Qb + NX;
    float* Vb     = Kb + NX;
    float* Ob     = Vb + NX;
    float* FFNH   = Ob + NX;                       // 8,388,608
    // decoder phase (aliases into R; encoder scratch dead):
    float* WEFF_t = R;                             // 4,194,304
    float* G2     = R + 4194304;                   // 3,276,800 (dead after tr_cat B)
    float* WT_A   = R + 7471104;                   // 6,291,456 (4096 x 1536)
    float* WT_B   = R + 13762560;                  // 8,388,608 (4096 x 2048)
    float* Hall   = R + 22151168;                  // 8,388,608 (B*S x 1024)
    float* T1     = WEFF_t;                        // 2,244,608 (after WT_B built)
    float* TAIL   = R + 34603008;
    float* G3v    = TAIL;                          // 4096
    // h-ring slots (ring_slot): [R+30539776, +248*16K) gap after Hall;
    //                           [R+4210688, +199*16K) dead G2 past BAR page;
    //                           [R+2244608, +66*16K)  dead T1 tail.
    // All are scan-dead regions; addresses used once each.
    unsigned* BAR = (unsigned*)G2;                 // 2080 uints (< 64KB page)

    const int M = B_ * S_; // 8192
    dim3 blk(256);

    // ---- encoder ----
    gemm128<<<dim3(M / 128, (DM_ + 127) / 128), blk, 0, stream>>>(
        src_seq, emb_W, X, M, DM_, FRAME_, emb_b, nullptr, src_pos, pos_tab, 0);
    gemm128<<<dim3(M / 128, (DM_ + 127) / 128), blk, 0, stream>>>(
        X, Wq, Qb, M, DM_, DM_, nullptr, nullptr, nullptr, nullptr, 0);
    gemm128<<<dim3(M / 128, (DM_ + 127) / 128), blk, 0, stream>>>(
        X, Wk, Kb, M, DM_, DM_, nullptr, nullptr, nullptr, nullptr, 0);
    gemm128<<<dim3(M / 128, (DM_ + 127) / 128), blk, 0, stream>>>(
        X, Wv, Vb, M, DM_, DM_, nullptr, nullptr, nullptr, nullptr, 0);
    attn_f32<<<dim3(B_ * H_ * (S_ / 4)), blk, 0, stream>>>(Qb, Kb, Vb, Ob);
    gemm128<<<dim3(M / 128, (DM_ + 127) / 128), blk, 0, stream>>>(
        Ob, Wo, FFNH, M, DM_, DM_, nullptr, X, nullptr, nullptr, 0);
    ln_f32<<<dim3(M), blk, 0, stream>>>(FFNH, X, ln1_g, ln1_b, DM_);
    gemm128<<<dim3(M / 128, FFN_ / 128), blk, 0, stream>>>(
        X, ffn_W1, FFNH, M, FFN_, DM_, ffn_b1, nullptr, nullptr, nullptr, 1);
    gemm128<<<dim3(M / 128, (DM_ + 127) / 128), blk, 0, stream>>>(
        FFNH, ffn_W2, Ob, M, DM_, FFN_, ffn_b2, X, nullptr, nullptr, 0);
    ln_f32<<<dim3(M), blk, 0, stream>>>(Ob, X, ln2_g, ln2_b, DM_);   // X = enc

    // ---- decoder precompute ----
    // WEFF_t = out_W[:1024]@lstm_Wx + lstm_Wh   (1024 x 4096)
    gemm128<<<dim3(HID_ / 128, G4_ / 128), blk, 0, stream>>>(
        out_W, lstm_Wx, WEFF_t, HID_, G4_, POSE_, nullptr, lstm_Wh, nullptr, nullptr, 0);
    // G2 = out_W[1024:]@lstm_Wx   (800 x 4096)
    gemm128<<<dim3((DM_ + 127) / 128, G4_ / 128), blk, 0, stream>>>(
        out_W + (long)HID_ * POSE_, lstm_Wx, G2, DM_, G4_, POSE_,
        nullptr, nullptr, nullptr, nullptr, 0);
    // transposed, zero-padded step weights
    tr_cat<<<dim3(KPA_ / 64, G4_ / 64), blk, 0, stream>>>(
        lstm_Wh, lstm_Wx, WT_A, HID_, POSE_, KPA_);
    tr_cat<<<dim3(KPB_ / 64, G4_ / 64), blk, 0, stream>>>(
        WEFF_t, G2, WT_B, HID_, DM_, KPB_);
    g3_kernel<<<dim3(G4_ / 256), blk, 0, stream>>>(out_b, lstm_Wx, G3v);
    // init h into ring slot 0 + zero barrier state (G2 is dead by now)
    init_state<<<dim3((B_ * HID_ + 255) / 256), blk, 0, stream>>>(
        vec_h, ring_slot(R, 0), BAR);
    // T1 = enc@out_W[1024:,:] + out_b  (aliases WEFF_t -> must follow tr_cat)
    gemm128<<<dim3(M / 128, (POSE_ + 127) / 128), blk, 0, stream>>>(
        X, out_W + (long)HID_ * POSE_, T1, M, POSE_, DM_, out_b,
        nullptr, nullptr, nullptr, 0);

    // ---- fused sequential scan: persistent kernel, fresh-address h ring ----
    lstm_scan<<<dim3(NBLK_SCAN), blk, 0, stream>>>(
        R, vec_c, WT_A, WT_B, G3v, lstm_b, epoch,
        tgt_seq, dec0, X, Hall, BAR);

    // ---- final: out = Hall@out_W[:1024] + T1 ----
    gemm128<<<dim3(M / 128, (POSE_ + 127) / 128), blk, 0, stream>>>(
        Hall, out_W, (float*)d_out, M, POSE_, HID_, nullptr, T1,
        nullptr, nullptr, 0);
}